// Round 4
// baseline (4832.665 us; speedup 1.0000x reference)
//
#include <hip/hip_runtime.h>

#define D       256
#define NHEADS  8
#define DH      32
#define FFDIM   1024
#define VOCAB   2048
#define GENLEN  16
#define BATCH   8
#define NSLOT   7
#define TF      17
#define NLAYER  4

#define SCOPE_AGENT __HIP_MEMORY_SCOPE_AGENT

struct Params {
  const float *slots, *W_slot_proj, *dict_emb, *pe;
  const float *ln_self_w, *ln_self_b, *Wq_s, *Wk_s, *Wv_s, *Wo_s;
  const float *ln_cross_w, *ln_cross_b, *Wq_c, *Wk_c, *Wv_c, *Wo_c;
  const float *ln_ffn_w, *ln_ffn_b, *W1, *b1, *W2, *b2;
  const float *ln_f_w, *ln_f_b, *W_out;
  float *enc, *P0, *P1, *tri;
  unsigned long long *bars;
  float *out_z, *out_lp;
};

__device__ __forceinline__ float cload(const float* p) {
  return __hip_atomic_load(p, __ATOMIC_RELAXED, SCOPE_AGENT);
}
__device__ __forceinline__ void cstore(float* p, float v) {
  __hip_atomic_store(p, v, __ATOMIC_RELAXED, SCOPE_AGENT);
}

__device__ __forceinline__ float blockSum(float v, float* red) {
  #pragma unroll
  for (int o = 32; o > 0; o >>= 1) v += __shfl_down(v, o);
  const int lane = threadIdx.x & 63, w = threadIdx.x >> 6;
  if (lane == 0) red[w] = v;
  __syncthreads();
  float s = red[0] + red[1] + red[2] + red[3];
  __syncthreads();
  return s;
}

// GEMV column dot with 16-deep load batching (MLP): acc += sum_{u<N} h[i0+u]*W[(i0+u)*ld]
template<int N>
__device__ __forceinline__ float dotCol(const float* __restrict__ W,
                                        const float* __restrict__ h,
                                        int i0, int ld) {
  float acc = 0.f;
  #pragma unroll
  for (int u = 0; u < N; u += 16) {
    float w[16];
    #pragma unroll
    for (int k = 0; k < 16; ++k) w[k] = W[(size_t)(i0 + u + k) * ld];
    #pragma unroll
    for (int k = 0; k < 16; ++k) acc = fmaf(h[i0 + u + k], w[k], acc);
  }
  return acc;
}

__global__ __launch_bounds__(256) void mega_kernel(Params p)
{
  const int blk = blockIdx.x;
  const int bb = blk >> 3, sl = blk & 7, tid = threadIdx.x;
  unsigned long long* bar = p.bars + bb * 128;   // 1 KB apart per batch group
  unsigned target = 0;

  __shared__ float hsh[D], qsh[DH], osh[DH], score[TF], red[4];
  __shared__ float ash[128];
  __shared__ float sval[256];
  __shared__ int   sidx[256];
  __shared__ float stage[NSLOT * D];
  __shared__ float kls[NLAYER][TF][DH + 1], vls[NLAYER][TF][DH + 1];       // self K/V (LDS-resident)
  __shared__ float kcls[NLAYER][NSLOT][DH + 1], vcls[NLAYER][NSLOT][DH + 1]; // cross K/V

  auto gbar = [&]() {
    ++target;
    __syncthreads();   // compiler drains vmcnt before s_barrier -> coherent stores retired
    if (tid == 0) {
      unsigned long long old =
          __hip_atomic_fetch_add(bar, 1ull, __ATOMIC_RELAXED, SCOPE_AGENT);
      if ((old & 0xffffffffull) == 7ull) {
        __hip_atomic_store(bar, ((unsigned long long)target) << 32,
                           __ATOMIC_RELAXED, SCOPE_AGENT);
      } else {
        while ((unsigned)(__hip_atomic_load(bar, __ATOMIC_RELAXED, SCOPE_AGENT) >> 32)
               < target)
          __builtin_amdgcn_s_sleep(1);
      }
    }
    __syncthreads();
    asm volatile("" ::: "memory");
  };

  auto layernorm = [&](float xv, const float* w, const float* b) -> float {
    const float mean = blockSum(xv, red) * (1.f / D);
    const float dv = xv - mean;
    const float var = blockSum(dv * dv, red) * (1.f / D);
    return dv * (1.f / sqrtf(var + 1e-5f)) * w[tid] + b[tid];
  };

  auto fold = [&](const float* P) -> float {
    float s[8];
    #pragma unroll
    for (int j = 0; j < 8; ++j) s[j] = cload(&P[(bb * 8 + j) * D + tid]);
    return ((s[0] + s[1]) + (s[2] + s[3])) + ((s[4] + s[5]) + (s[6] + s[7]));
  };

  float heldLogit = 0.f;   // this block's logit for col sl*256+tid (persists across stages)
  int   lastAmax  = 0;

  auto consume_tri = [&](int row) {
    float tmax[8], tsum[8]; int tix[8];
    #pragma unroll
    for (int j = 0; j < 8; ++j) tmax[j] = cload(&p.tri[(bb * 8 + j) * 8 + 0]);
    #pragma unroll
    for (int j = 0; j < 8; ++j) tsum[j] = cload(&p.tri[(bb * 8 + j) * 8 + 1]);
    #pragma unroll
    for (int j = 0; j < 8; ++j) tix[j] = (int)cload(&p.tri[(bb * 8 + j) * 8 + 2]);
    float gm = tmax[0];
    #pragma unroll
    for (int j = 1; j < 8; ++j) gm = fmaxf(gm, tmax[j]);
    float gs = 0.f;
    #pragma unroll
    for (int j = 0; j < 8; ++j) gs += tsum[j] * expf(tmax[j] - gm);
    const float lse = gm + logf(gs);
    float best = -1e30f; int am = 0;
    #pragma unroll
    for (int j = 0; j < 8; ++j)
      if (tmax[j] > best) { best = tmax[j]; am = j * 256 + tix[j]; }  // strict > : first-index ties
    p.out_lp[(bb * GENLEN + row) * VOCAB + sl * 256 + tid] = heldLogit - lse;
    if (sl == 0 && tid == 0)
      p.out_z[bb * VOCAB * GENLEN + am * GENLEN + row] = 1.0f;
    lastAmax = am;
  };

  // ================= init: enc = slots @ W_slot_proj (this block: cols sl*32..) ========
  if (tid < 32) {
    const int c = sl * 32 + tid;
    float acc[NSLOT] = {0.f,0.f,0.f,0.f,0.f,0.f,0.f};
    #pragma unroll 8
    for (int i = 0; i < D; ++i) {
      const float w = p.W_slot_proj[i * D + c];
      #pragma unroll
      for (int s = 0; s < NSLOT; ++s) acc[s] += p.slots[(bb * NSLOT + s) * D + i] * w;
    }
    for (int s = 0; s < NSLOT; ++s) cstore(&p.enc[(bb * NSLOT + s) * D + c], acc[s]);
  }
  gbar();

  // ============ init: cross K/V for this block's head -> LDS (block-local forever) =====
  {
    for (int i = tid; i < NSLOT * D; i += 256) stage[i] = cload(&p.enc[bb * NSLOT * D + i]);
    __syncthreads();
    const int l = tid >> 6, g = tid & 63, c32 = g >> 1, mat = g & 1;
    const float* W = (mat ? p.Wv_c : p.Wk_c) + l * D * D + sl * DH + c32;
    float acc[NSLOT] = {0.f,0.f,0.f,0.f,0.f,0.f,0.f};
    #pragma unroll 8
    for (int i = 0; i < D; ++i) {
      const float w = W[i * D];
      #pragma unroll
      for (int s = 0; s < NSLOT; ++s) acc[s] += stage[s * D + i] * w;
    }
    if (mat) { for (int s = 0; s < NSLOT; ++s) vcls[l][s][c32] = acc[s]; }
    else     { for (int s = 0; s < NSLOT; ++s) kcls[l][s][c32] = acc[s]; }
    __syncthreads();
  }

  float* Pbuf[2] = {p.P0, p.P1};
  int par = 0;
  float x = 0.f;   // replicated residual component tid for batch bb (identical in all 8 blocks)

  // ================================ generation loop ================================
  for (int t = 0; t < GENLEN; ++t) {
    for (int l = 0; l < NLAYER; ++l) {
      // ------------------------------- SELF-ATTN -------------------------------
      {
        if (l == 0) {
          int tok = 0;
          if (t > 0) { consume_tri(t - 1); tok = lastAmax + 1; }
          x = p.dict_emb[tok * D + tid] + p.pe[t * D + tid];
        } else {
          x += fold(Pbuf[par]);
        }
        const float h = layernorm(x, p.ln_self_w + l * D, p.ln_self_b + l * D);
        if (l == 0) x = h;                    // SLATE quirk (replicated identically)
        hsh[tid] = h;
        __syncthreads();

        // QKV for head sl: 192 threads, split-K x2 per column
        if (tid < 192) {
          const int mm = tid >> 6, g = tid & 63, c32 = g >> 1, half = g & 1;
          const int c = sl * DH + c32;
          const float* W = (mm == 0 ? p.Wq_s : (mm == 1 ? p.Wk_s : p.Wv_s)) + l * D * D + c;
          float acc = dotCol<128>(W, hsh, half * 128, D);
          acc += __shfl_xor(acc, 1);
          if (half == 0) {
            if (mm == 0)      qsh[c32] = acc * 0.17677669529663689f;   // dh^-0.5
            else if (mm == 1) kls[l][t][c32] = acc;
            else              vls[l][t][c32] = acc;
          }
        }
        __syncthreads();

        if (tid <= t) {
          float a = 0.f;
          #pragma unroll
          for (int r = 0; r < DH; ++r) a += qsh[r] * kls[l][tid][r];
          score[tid] = a;
        }
        __syncthreads();
        if (tid == 0) {
          float mx = -1e30f;
          for (int i = 0; i <= t; ++i) mx = fmaxf(mx, score[i]);
          float s2 = 0.f;
          for (int i = 0; i <= t; ++i) { const float e = expf(score[i] - mx); score[i] = e; s2 += e; }
          const float inv = 1.f / s2;
          for (int i = 0; i <= t; ++i) score[i] *= inv;
        }
        __syncthreads();
        if (tid < DH) {
          float a = 0.f;
          for (int pp = 0; pp <= t; ++pp) a += score[pp] * vls[l][pp][tid];
          osh[tid] = a;
        }
        __syncthreads();
        // Wo row-slice partial
        {
          const float a = dotCol<DH>(p.Wo_s + l * D * D + sl * DH * D + tid, osh, 0, D);
          cstore(&Pbuf[par ^ 1][(bb * 8 + sl) * D + tid], a);
        }
      }
      gbar(); par ^= 1;

      // ------------------------------- CROSS-ATTN -------------------------------
      {
        x += fold(Pbuf[par]);
        hsh[tid] = layernorm(x, p.ln_cross_w + l * D, p.ln_cross_b + l * D);
        __syncthreads();

        // q for head sl: 256 threads, split-K x8 per column
        {
          const int c32 = tid >> 3, sub = tid & 7;
          const float* W = p.Wq_c + l * D * D + sl * DH + c32;
          float acc = dotCol<32>(W, hsh, sub * 32, D);
          acc += __shfl_xor(acc, 1);
          acc += __shfl_xor(acc, 2);
          acc += __shfl_xor(acc, 4);
          if (sub == 0) qsh[c32] = acc * 0.17677669529663689f;
        }
        __syncthreads();
        if (tid < NSLOT) {
          float a = 0.f;
          #pragma unroll
          for (int r = 0; r < DH; ++r) a += qsh[r] * kcls[l][tid][r];
          score[tid] = a;
        }
        __syncthreads();
        if (tid == 0) {
          float mx = -1e30f;
          for (int i = 0; i < NSLOT; ++i) mx = fmaxf(mx, score[i]);
          float s2 = 0.f;
          for (int i = 0; i < NSLOT; ++i) { const float e = expf(score[i] - mx); score[i] = e; s2 += e; }
          const float inv = 1.f / s2;
          for (int i = 0; i < NSLOT; ++i) score[i] *= inv;
        }
        __syncthreads();
        if (tid < DH) {
          float a = 0.f;
          #pragma unroll
          for (int s = 0; s < NSLOT; ++s) a += score[s] * vcls[l][s][tid];
          osh[tid] = a;
        }
        __syncthreads();
        {
          const float a = dotCol<DH>(p.Wo_c + l * D * D + sl * DH * D + tid, osh, 0, D);
          cstore(&Pbuf[par ^ 1][(bb * 8 + sl) * D + tid], a);
        }
      }
      gbar(); par ^= 1;

      // ---------------------------------- FFN ----------------------------------
      {
        x += fold(Pbuf[par]);
        hsh[tid] = layernorm(x, p.ln_ffn_w + l * D, p.ln_ffn_b + l * D);
        __syncthreads();

        // W1 slice: 128 cols, split-K x2
        {
          const int c128 = tid >> 1, half = tid & 1, c = sl * 128 + c128;
          float acc = dotCol<128>(p.W1 + l * D * FFDIM + c, hsh, half * 128, FFDIM);
          acc += __shfl_xor(acc, 1);
          if (half == 0) ash[c128] = fmaxf(acc + p.b1[l * FFDIM + c], 0.f);
        }
        __syncthreads();
        // W2 row-slice partial (b2 folded into slice 0's partial)
        {
          float acc = dotCol<128>(p.W2 + l * FFDIM * D + sl * 128 * D + tid, ash, 0, D);
          if (sl == 0) acc += p.b2[l * D + tid];
          cstore(&Pbuf[par ^ 1][(bb * 8 + sl) * D + tid], acc);
        }
        __syncthreads();   // ash stable until all threads done
      }
      gbar(); par ^= 1;
    }

    // --------------------------------- LOGITS ---------------------------------
    {
      x += fold(Pbuf[par]);
      hsh[tid] = layernorm(x, p.ln_f_w, p.ln_f_b);
      __syncthreads();
      heldLogit = dotCol<256>(p.W_out + sl * 256 + tid, hsh, 0, VOCAB);

      // slice-local {max, argmax(first), sumexp} -> triple
      sval[tid] = heldLogit; sidx[tid] = tid;
      __syncthreads();
      for (int s = 128; s; s >>= 1) {
        if (tid < s) {
          float v2 = sval[tid + s]; int i2 = sidx[tid + s];
          if (v2 > sval[tid] || (v2 == sval[tid] && i2 < sidx[tid])) { sval[tid] = v2; sidx[tid] = i2; }
        }
        __syncthreads();
      }
      const float smax = sval[0]; const int sarg = sidx[0];
      __syncthreads();
      const float ssum = blockSum(expf(heldLogit - smax), red);
      if (tid == 0) {
        cstore(&p.tri[(bb * 8 + sl) * 8 + 0], smax);
        cstore(&p.tri[(bb * 8 + sl) * 8 + 1], ssum);
        cstore(&p.tri[(bb * 8 + sl) * 8 + 2], (float)sarg);
      }
      __syncthreads();   // hsh/sval stable
    }
    gbar();
  }

  // ------------------------------ final step output ------------------------------
  consume_tri(GENLEN - 1);
}

extern "C" void kernel_launch(void* const* d_in, const int* in_sizes, int n_in,
                              void* d_out, int out_size, void* d_ws, size_t ws_size,
                              hipStream_t stream)
{
  Params p;
  const float* const* in = (const float* const*)d_in;
  p.slots = in[0];  p.W_slot_proj = in[1]; p.dict_emb = in[2]; p.pe = in[3];
  p.ln_self_w = in[4];  p.ln_self_b = in[5];
  p.Wq_s = in[6];  p.Wk_s = in[7];  p.Wv_s = in[8];  p.Wo_s = in[9];
  p.ln_cross_w = in[10]; p.ln_cross_b = in[11];
  p.Wq_c = in[12]; p.Wk_c = in[13]; p.Wv_c = in[14]; p.Wo_c = in[15];
  p.ln_ffn_w = in[16]; p.ln_ffn_b = in[17];
  p.W1 = in[18]; p.b1 = in[19]; p.W2 = in[20]; p.b2 = in[21];
  p.ln_f_w = in[22]; p.ln_f_b = in[23]; p.W_out = in[24];

  p.bars = (unsigned long long*)d_ws;                  // 8 groups x 128 ull (1 KB each)
  float* ws = (float*)d_ws + BATCH * 128 * 2;
  p.enc = ws;  ws += BATCH * NSLOT * D;
  p.P0  = ws;  ws += BATCH * 8 * D;
  p.P1  = ws;  ws += BATCH * 8 * D;
  p.tri = ws;  ws += BATCH * 8 * 8;

  p.out_z  = (float*)d_out;
  p.out_lp = (float*)d_out + BATCH * VOCAB * GENLEN;

  hipMemsetAsync(d_ws, 0, BATCH * 128 * sizeof(unsigned long long), stream);
  hipMemsetAsync(d_out, 0, (size_t)out_size * sizeof(float), stream);

  mega_kernel<<<64, 256, 0, stream>>>(p);
}

// Round 5
// 4815.340 us; speedup vs baseline: 1.0036x; 1.0036x over previous
//
#include <hip/hip_runtime.h>

#define D       256
#define NHEADS  8
#define DH      32
#define FFDIM   1024
#define VOCAB   2048
#define GENLEN  16
#define BATCH   8
#define NSLOT   7
#define TF      17
#define NLAYER  4

#define SCOPE_AGENT __HIP_MEMORY_SCOPE_AGENT

struct Params {
  const float *slots, *W_slot_proj, *dict_emb, *pe;
  const float *ln_self_w, *ln_self_b, *Wq_s, *Wk_s, *Wv_s, *Wo_s;
  const float *ln_cross_w, *ln_cross_b, *Wq_c, *Wk_c, *Wv_c, *Wo_c;
  const float *ln_ffn_w, *ln_ffn_b, *W1, *b1, *W2, *b2;
  const float *ln_f_w, *ln_f_b, *W_out;
  float *enc, *P0, *P1, *tri;
  unsigned long long *bars;
  float *out_z, *out_lp;
};

__device__ __forceinline__ float cload(const float* p) {
  return __hip_atomic_load(p, __ATOMIC_RELAXED, SCOPE_AGENT);
}
__device__ __forceinline__ void cstore(float* p, float v) {
  __hip_atomic_store(p, v, __ATOMIC_RELAXED, SCOPE_AGENT);
}

__device__ __forceinline__ float blockSum(float v, float* red) {
  #pragma unroll
  for (int o = 32; o > 0; o >>= 1) v += __shfl_down(v, o);
  const int lane = threadIdx.x & 63, w = threadIdx.x >> 6;
  if (lane == 0) red[w] = v;
  __syncthreads();
  float s = red[0] + red[1] + red[2] + red[3];
  __syncthreads();
  return s;
}

// GEMV column dot with 16-deep load batching (MLP): acc += sum_{u<N} h[i0+u]*W[(i0+u)*ld]
template<int N>
__device__ __forceinline__ float dotCol(const float* __restrict__ W,
                                        const float* __restrict__ h,
                                        int i0, int ld) {
  float acc = 0.f;
  #pragma unroll
  for (int u = 0; u < N; u += 16) {
    float w[16];
    #pragma unroll
    for (int k = 0; k < 16; ++k) w[k] = W[(size_t)(i0 + u + k) * ld];
    #pragma unroll
    for (int k = 0; k < 16; ++k) acc = fmaf(h[i0 + u + k], w[k], acc);
  }
  return acc;
}

// 1 block/CU, 1 wave/SIMD -> allow up to ~512 VGPRs, no spill (round-4 lesson)
__global__ __launch_bounds__(256, 1) void mega_kernel(Params p)
{
  const int blk = blockIdx.x;
  const int bb = blk >> 3, sl = blk & 7, tid = threadIdx.x;
  unsigned long long* bar = p.bars + bb * 128;   // 1 KB apart per batch group
  unsigned target = 0;

  __shared__ float hsh[D], qsh[DH], osh[DH], score[TF], red[4];
  __shared__ float ash[128];
  __shared__ float sval[256];
  __shared__ int   sidx[256];
  __shared__ float stage[NSLOT * D];
  __shared__ float kls[NLAYER][TF][DH + 1], vls[NLAYER][TF][DH + 1];         // self K/V (LDS)
  __shared__ float kcls[NLAYER][NSLOT][DH + 1], vcls[NLAYER][NSLOT][DH + 1]; // cross K/V

  auto gbar = [&]() {
    ++target;
    __syncthreads();   // drains vmcnt -> coherent stores retired before arrive
    if (tid == 0) {
      unsigned long long old =
          __hip_atomic_fetch_add(bar, 1ull, __ATOMIC_RELAXED, SCOPE_AGENT);
      if ((old & 0xffffffffull) == 7ull) {
        __hip_atomic_store(bar, ((unsigned long long)target) << 32,
                           __ATOMIC_RELAXED, SCOPE_AGENT);
      } else {
        while ((unsigned)(__hip_atomic_load(bar, __ATOMIC_RELAXED, SCOPE_AGENT) >> 32)
               < target)
          __builtin_amdgcn_s_sleep(1);
      }
    }
    __syncthreads();
    asm volatile("" ::: "memory");
  };

  auto layernorm = [&](float xv, const float* w, const float* b) -> float {
    const float mean = blockSum(xv, red) * (1.f / D);
    const float dv = xv - mean;
    const float var = blockSum(dv * dv, red) * (1.f / D);
    return dv * (1.f / sqrtf(var + 1e-5f)) * w[tid] + b[tid];
  };

  auto fold = [&](const float* P) -> float {
    float s[8];
    #pragma unroll
    for (int j = 0; j < 8; ++j) s[j] = cload(&P[(bb * 8 + j) * D + tid]);
    return ((s[0] + s[1]) + (s[2] + s[3])) + ((s[4] + s[5]) + (s[6] + s[7]));
  };

  float heldLogit = 0.f;   // this block's logit for col sl*256+tid
  int   lastAmax  = 0;

  // streamed combine: low register footprint (round-4 spill lesson)
  auto consume_tri = [&](int row) {
    float tmax[8];
    #pragma unroll
    for (int j = 0; j < 8; ++j) tmax[j] = cload(&p.tri[(bb * 8 + j) * 8 + 0]);
    float gm = tmax[0];
    #pragma unroll
    for (int j = 1; j < 8; ++j) gm = fmaxf(gm, tmax[j]);
    float gs = 0.f;
    float best = -1e30f; int am = 0;
    #pragma unroll
    for (int j = 0; j < 8; ++j) {
      gs += cload(&p.tri[(bb * 8 + j) * 8 + 1]) * expf(tmax[j] - gm);
      if (tmax[j] > best) {                      // strict > : first-index tie-break
        best = tmax[j];
        am = j * 256 + (int)cload(&p.tri[(bb * 8 + j) * 8 + 2]);
      }
    }
    const float lse = gm + logf(gs);
    p.out_lp[(bb * GENLEN + row) * VOCAB + sl * 256 + tid] = heldLogit - lse;
    if (sl == 0 && tid == 0)
      p.out_z[bb * VOCAB * GENLEN + am * GENLEN + row] = 1.0f;
    lastAmax = am;
  };

  // ================= init: enc = slots @ W_slot_proj (cols sl*32..) =================
  if (tid < 32) {
    const int c = sl * 32 + tid;
    float acc[NSLOT] = {0.f,0.f,0.f,0.f,0.f,0.f,0.f};
    #pragma unroll 8
    for (int i = 0; i < D; ++i) {
      const float w = p.W_slot_proj[i * D + c];
      #pragma unroll
      for (int s = 0; s < NSLOT; ++s) acc[s] += p.slots[(bb * NSLOT + s) * D + i] * w;
    }
    for (int s = 0; s < NSLOT; ++s) cstore(&p.enc[(bb * NSLOT + s) * D + c], acc[s]);
  }
  gbar();

  // ============ init: cross K/V for this block's head -> LDS (block-local) ============
  {
    for (int i = tid; i < NSLOT * D; i += 256) stage[i] = cload(&p.enc[bb * NSLOT * D + i]);
    __syncthreads();
    const int l = tid >> 6, g = tid & 63, c32 = g >> 1, mat = g & 1;
    const float* W = (mat ? p.Wv_c : p.Wk_c) + l * D * D + sl * DH + c32;
    float acc[NSLOT] = {0.f,0.f,0.f,0.f,0.f,0.f,0.f};
    #pragma unroll 8
    for (int i = 0; i < D; ++i) {
      const float w = W[i * D];
      #pragma unroll
      for (int s = 0; s < NSLOT; ++s) acc[s] += stage[s * D + i] * w;
    }
    if (mat) { for (int s = 0; s < NSLOT; ++s) vcls[l][s][c32] = acc[s]; }
    else     { for (int s = 0; s < NSLOT; ++s) kcls[l][s][c32] = acc[s]; }
    __syncthreads();
  }

  float* Pbuf[2] = {p.P0, p.P1};
  int par = 0;
  float x = 0.f;   // replicated residual (identical bits in all 8 slice-blocks)

  // ================================ generation loop ================================
  for (int t = 0; t < GENLEN; ++t) {
    for (int l = 0; l < NLAYER; ++l) {
      // ------------------------------- SELF-ATTN -------------------------------
      {
        if (l == 0) {
          int tok = 0;
          if (t > 0) { consume_tri(t - 1); tok = lastAmax + 1; }
          x = p.dict_emb[tok * D + tid] + p.pe[t * D + tid];
        } else {
          x += fold(Pbuf[par]);
        }
        const float h = layernorm(x, p.ln_self_w + l * D, p.ln_self_b + l * D);
        if (l == 0) x = h;                    // SLATE quirk
        hsh[tid] = h;
        __syncthreads();

        // QKV for head sl: 192 threads, split-K x2 per column
        if (tid < 192) {
          const int mm = tid >> 6, g = tid & 63, c32 = g >> 1, half = g & 1;
          const int c = sl * DH + c32;
          const float* W = (mm == 0 ? p.Wq_s : (mm == 1 ? p.Wk_s : p.Wv_s)) + l * D * D + c;
          float acc = dotCol<128>(W, hsh, half * 128, D);
          acc += __shfl_xor(acc, 1);
          if (half == 0) {
            if (mm == 0)      qsh[c32] = acc * 0.17677669529663689f;   // dh^-0.5
            else if (mm == 1) kls[l][t][c32] = acc;
            else              vls[l][t][c32] = acc;
          }
        }
        __syncthreads();

        if (tid <= t) {
          float a = 0.f;
          #pragma unroll
          for (int r = 0; r < DH; ++r) a += qsh[r] * kls[l][tid][r];
          score[tid] = a;
        }
        __syncthreads();
        if (tid == 0) {
          float mx = -1e30f;
          for (int i = 0; i <= t; ++i) mx = fmaxf(mx, score[i]);
          float s2 = 0.f;
          for (int i = 0; i <= t; ++i) { const float e = expf(score[i] - mx); score[i] = e; s2 += e; }
          const float inv = 1.f / s2;
          for (int i = 0; i <= t; ++i) score[i] *= inv;
        }
        __syncthreads();
        if (tid < DH) {
          float a = 0.f;
          for (int pp = 0; pp <= t; ++pp) a += score[pp] * vls[l][pp][tid];
          osh[tid] = a;
        }
        __syncthreads();
        {
          const float a = dotCol<DH>(p.Wo_s + l * D * D + sl * DH * D + tid, osh, 0, D);
          cstore(&Pbuf[par ^ 1][(bb * 8 + sl) * D + tid], a);
        }
      }
      gbar(); par ^= 1;

      // ------------------------------- CROSS-ATTN -------------------------------
      {
        x += fold(Pbuf[par]);
        hsh[tid] = layernorm(x, p.ln_cross_w + l * D, p.ln_cross_b + l * D);
        __syncthreads();

        // q for head sl: 256 threads, split-K x8 per column
        {
          const int c32 = tid >> 3, sub = tid & 7;
          const float* W = p.Wq_c + l * D * D + sl * DH + c32;
          float acc = dotCol<32>(W, hsh, sub * 32, D);
          acc += __shfl_xor(acc, 1);
          acc += __shfl_xor(acc, 2);
          acc += __shfl_xor(acc, 4);
          if (sub == 0) qsh[c32] = acc * 0.17677669529663689f;
        }
        __syncthreads();
        if (tid < NSLOT) {
          float a = 0.f;
          #pragma unroll
          for (int r = 0; r < DH; ++r) a += qsh[r] * kcls[l][tid][r];
          score[tid] = a;
        }
        __syncthreads();
        if (tid == 0) {
          float mx = -1e30f;
          for (int i = 0; i < NSLOT; ++i) mx = fmaxf(mx, score[i]);
          float s2 = 0.f;
          for (int i = 0; i < NSLOT; ++i) { const float e = expf(score[i] - mx); score[i] = e; s2 += e; }
          const float inv = 1.f / s2;
          for (int i = 0; i < NSLOT; ++i) score[i] *= inv;
        }
        __syncthreads();
        if (tid < DH) {
          float a = 0.f;
          #pragma unroll
          for (int s = 0; s < NSLOT; ++s) a += score[s] * vcls[l][s][tid];
          osh[tid] = a;
        }
        __syncthreads();
        {
          const float a = dotCol<DH>(p.Wo_c + l * D * D + sl * DH * D + tid, osh, 0, D);
          cstore(&Pbuf[par ^ 1][(bb * 8 + sl) * D + tid], a);
        }
      }
      gbar(); par ^= 1;

      // ---------------------------------- FFN ----------------------------------
      {
        x += fold(Pbuf[par]);
        hsh[tid] = layernorm(x, p.ln_ffn_w + l * D, p.ln_ffn_b + l * D);
        __syncthreads();

        // W1 slice: 128 cols, split-K x2
        {
          const int c128 = tid >> 1, half = tid & 1, c = sl * 128 + c128;
          float acc = dotCol<128>(p.W1 + l * D * FFDIM + c, hsh, half * 128, FFDIM);
          acc += __shfl_xor(acc, 1);
          if (half == 0) ash[c128] = fmaxf(acc + p.b1[l * FFDIM + c], 0.f);
        }
        __syncthreads();
        // W2 row-slice partial (b2 folded into slice 0)
        {
          float acc = dotCol<128>(p.W2 + l * FFDIM * D + sl * 128 * D + tid, ash, 0, D);
          if (sl == 0) acc += p.b2[l * D + tid];
          cstore(&Pbuf[par ^ 1][(bb * 8 + sl) * D + tid], acc);
        }
        __syncthreads();
      }
      gbar(); par ^= 1;
    }

    // --------------------------------- LOGITS ---------------------------------
    {
      x += fold(Pbuf[par]);
      hsh[tid] = layernorm(x, p.ln_f_w, p.ln_f_b);
      __syncthreads();
      heldLogit = dotCol<256>(p.W_out + sl * 256 + tid, hsh, 0, VOCAB);

      sval[tid] = heldLogit; sidx[tid] = tid;
      __syncthreads();
      for (int s = 128; s; s >>= 1) {
        if (tid < s) {
          float v2 = sval[tid + s]; int i2 = sidx[tid + s];
          if (v2 > sval[tid] || (v2 == sval[tid] && i2 < sidx[tid])) { sval[tid] = v2; sidx[tid] = i2; }
        }
        __syncthreads();
      }
      const float smax = sval[0]; const int sarg = sidx[0];
      __syncthreads();
      const float ssum = blockSum(expf(heldLogit - smax), red);
      if (tid == 0) {
        cstore(&p.tri[(bb * 8 + sl) * 8 + 0], smax);
        cstore(&p.tri[(bb * 8 + sl) * 8 + 1], ssum);
        cstore(&p.tri[(bb * 8 + sl) * 8 + 2], (float)sarg);
      }
      __syncthreads();
    }
    gbar();
  }

  // ------------------------------ final step output ------------------------------
  consume_tri(GENLEN - 1);
}

extern "C" void kernel_launch(void* const* d_in, const int* in_sizes, int n_in,
                              void* d_out, int out_size, void* d_ws, size_t ws_size,
                              hipStream_t stream)
{
  Params p;
  const float* const* in = (const float* const*)d_in;
  p.slots = in[0];  p.W_slot_proj = in[1]; p.dict_emb = in[2]; p.pe = in[3];
  p.ln_self_w = in[4];  p.ln_self_b = in[5];
  p.Wq_s = in[6];  p.Wk_s = in[7];  p.Wv_s = in[8];  p.Wo_s = in[9];
  p.ln_cross_w = in[10]; p.ln_cross_b = in[11];
  p.Wq_c = in[12]; p.Wk_c = in[13]; p.Wv_c = in[14]; p.Wo_c = in[15];
  p.ln_ffn_w = in[16]; p.ln_ffn_b = in[17];
  p.W1 = in[18]; p.b1 = in[19]; p.W2 = in[20]; p.b2 = in[21];
  p.ln_f_w = in[22]; p.ln_f_b = in[23]; p.W_out = in[24];

  p.bars = (unsigned long long*)d_ws;                  // 8 groups x 128 ull (1 KB each)
  float* ws = (float*)d_ws + BATCH * 128 * 2;
  p.enc = ws;  ws += BATCH * NSLOT * D;
  p.P0  = ws;  ws += BATCH * 8 * D;
  p.P1  = ws;  ws += BATCH * 8 * D;
  p.tri = ws;  ws += BATCH * 8 * 8;

  p.out_z  = (float*)d_out;
  p.out_lp = (float*)d_out + BATCH * VOCAB * GENLEN;

  hipMemsetAsync(d_ws, 0, BATCH * 128 * sizeof(unsigned long long), stream);
  hipMemsetAsync(d_out, 0, (size_t)out_size * sizeof(float), stream);

  mega_kernel<<<64, 256, 0, stream>>>(p);
}

// Round 6
// 1576.323 us; speedup vs baseline: 3.0658x; 3.0548x over previous
//
#include <hip/hip_runtime.h>

#define D       256
#define NHEADS  8
#define DH      32
#define FFDIM   1024
#define VOCAB   2048
#define GENLEN  16
#define BATCH   8
#define NSLOT   7
#define TF      17
#define NLAYER  4

#define SCOPE_AGENT __HIP_MEMORY_SCOPE_AGENT

struct Params {
  const float *slots, *W_slot_proj, *dict_emb, *pe;
  const float *ln_self_w, *ln_self_b, *Wq_s, *Wk_s, *Wv_s, *Wo_s;
  const float *ln_cross_w, *ln_cross_b, *Wq_c, *Wk_c, *Wv_c, *Wo_c;
  const float *ln_ffn_w, *ln_ffn_b, *W1, *b1, *W2, *b2;
  const float *ln_f_w, *ln_f_b, *W_out;
  float *enc, *P0, *P1, *tri;
  unsigned long long *bars;
  float *out_z, *out_lp;
};

__device__ __forceinline__ float cload(const float* p) {
  return __hip_atomic_load(p, __ATOMIC_RELAXED, SCOPE_AGENT);
}
__device__ __forceinline__ void cstore(float* p, float v) {
  __hip_atomic_store(p, v, __ATOMIC_RELAXED, SCOPE_AGENT);
}

__device__ __forceinline__ float blockSum(float v, float* red) {
  #pragma unroll
  for (int o = 32; o > 0; o >>= 1) v += __shfl_down(v, o);
  const int lane = threadIdx.x & 63, w = threadIdx.x >> 6;
  if (lane == 0) red[w] = v;
  __syncthreads();
  float s = red[0] + red[1] + red[2] + red[3];
  __syncthreads();
  return s;
}

// GEMV column dot. BOUNDED live set: 32-deep load batch, outer loop NOT unrolled
// (round-4/5 lesson: full unroll let the scheduler keep N loads live -> VGPR spill
// -> 500MB scratch traffic). 32 loads in flight x 4 waves/CU ~ 32KB/CU: ~L2 BW-bound.
// h is LDS, read as float4 (i0 and batches are 32-aligned, so 16B alignment holds).
template<int N>
__device__ __forceinline__ float dotCol(const float* __restrict__ W,
                                        const float* __restrict__ h,
                                        int i0, int ld) {
  float acc = 0.f;
  #pragma unroll 1
  for (int u = 0; u < N; u += 32) {
    float w[32];
    #pragma unroll
    for (int k = 0; k < 32; ++k) w[k] = W[(size_t)(i0 + u + k) * ld];
    const float4* h4 = reinterpret_cast<const float4*>(h + i0 + u);
    #pragma unroll
    for (int k = 0; k < 8; ++k) {
      const float4 hv = h4[k];
      acc = fmaf(hv.x, w[4 * k + 0], acc);
      acc = fmaf(hv.y, w[4 * k + 1], acc);
      acc = fmaf(hv.z, w[4 * k + 2], acc);
      acc = fmaf(hv.w, w[4 * k + 3], acc);
    }
  }
  return acc;
}

__global__ __launch_bounds__(256, 1) void mega_kernel(Params p)
{
  const int blk = blockIdx.x;
  const int bb = blk >> 3, sl = blk & 7, tid = threadIdx.x;
  unsigned long long* bar = p.bars + bb * 128;   // 1 KB apart per batch group
  unsigned target = 0;

  __shared__ float hsh[D], qsh[DH], osh[DH], score[TF], red[4];
  __shared__ float ash[128];
  __shared__ float sval[256];
  __shared__ int   sidx[256];
  __shared__ float stage[NSLOT * D];
  __shared__ float kls[NLAYER][TF][DH + 1], vls[NLAYER][TF][DH + 1];         // self K/V (LDS)
  __shared__ float kcls[NLAYER][NSLOT][DH + 1], vcls[NLAYER][NSLOT][DH + 1]; // cross K/V

  auto gbar = [&]() {
    ++target;
    __syncthreads();   // drains vmcnt -> coherent stores retired before arrive
    if (tid == 0) {
      unsigned long long old =
          __hip_atomic_fetch_add(bar, 1ull, __ATOMIC_RELAXED, SCOPE_AGENT);
      if ((old & 0xffffffffull) == 7ull) {
        __hip_atomic_store(bar, ((unsigned long long)target) << 32,
                           __ATOMIC_RELAXED, SCOPE_AGENT);
      } else {
        while ((unsigned)(__hip_atomic_load(bar, __ATOMIC_RELAXED, SCOPE_AGENT) >> 32)
               < target)
          __builtin_amdgcn_s_sleep(1);
      }
    }
    __syncthreads();
    asm volatile("" ::: "memory");
  };

  auto layernorm = [&](float xv, const float* w, const float* b) -> float {
    const float mean = blockSum(xv, red) * (1.f / D);
    const float dv = xv - mean;
    const float var = blockSum(dv * dv, red) * (1.f / D);
    return dv * (1.f / sqrtf(var + 1e-5f)) * w[tid] + b[tid];
  };

  auto fold = [&](const float* P) -> float {
    float s[8];
    #pragma unroll
    for (int j = 0; j < 8; ++j) s[j] = cload(&P[(bb * 8 + j) * D + tid]);
    return ((s[0] + s[1]) + (s[2] + s[3])) + ((s[4] + s[5]) + (s[6] + s[7]));
  };

  float heldLogit = 0.f;   // this block's logit for col sl*256+tid
  int   lastAmax  = 0;

  // streamed combine: low register footprint
  auto consume_tri = [&](int row) {
    float tmax[8];
    #pragma unroll
    for (int j = 0; j < 8; ++j) tmax[j] = cload(&p.tri[(bb * 8 + j) * 8 + 0]);
    float gm = tmax[0];
    #pragma unroll
    for (int j = 1; j < 8; ++j) gm = fmaxf(gm, tmax[j]);
    float gs = 0.f;
    float best = -1e30f; int am = 0;
    #pragma unroll
    for (int j = 0; j < 8; ++j) {
      gs += cload(&p.tri[(bb * 8 + j) * 8 + 1]) * expf(tmax[j] - gm);
      if (tmax[j] > best) {                      // strict > : first-index tie-break
        best = tmax[j];
        am = j * 256 + (int)cload(&p.tri[(bb * 8 + j) * 8 + 2]);
      }
    }
    const float lse = gm + logf(gs);
    p.out_lp[(bb * GENLEN + row) * VOCAB + sl * 256 + tid] = heldLogit - lse;
    if (sl == 0 && tid == 0)
      p.out_z[bb * VOCAB * GENLEN + am * GENLEN + row] = 1.0f;
    lastAmax = am;
  };

  // ================= init: enc = slots @ W_slot_proj (cols sl*32..) =================
  if (tid < 32) {
    const int c = sl * 32 + tid;
    float acc[NSLOT] = {0.f,0.f,0.f,0.f,0.f,0.f,0.f};
    #pragma unroll 8
    for (int i = 0; i < D; ++i) {
      const float w = p.W_slot_proj[i * D + c];
      #pragma unroll
      for (int s = 0; s < NSLOT; ++s) acc[s] += p.slots[(bb * NSLOT + s) * D + i] * w;
    }
    for (int s = 0; s < NSLOT; ++s) cstore(&p.enc[(bb * NSLOT + s) * D + c], acc[s]);
  }
  gbar();

  // ============ init: cross K/V for this block's head -> LDS (block-local) ============
  {
    for (int i = tid; i < NSLOT * D; i += 256) stage[i] = cload(&p.enc[bb * NSLOT * D + i]);
    __syncthreads();
    const int l = tid >> 6, g = tid & 63, c32 = g >> 1, mat = g & 1;
    const float* W = (mat ? p.Wv_c : p.Wk_c) + l * D * D + sl * DH + c32;
    float acc[NSLOT] = {0.f,0.f,0.f,0.f,0.f,0.f,0.f};
    #pragma unroll 8
    for (int i = 0; i < D; ++i) {
      const float w = W[i * D];
      #pragma unroll
      for (int s = 0; s < NSLOT; ++s) acc[s] += stage[s * D + i] * w;
    }
    if (mat) { for (int s = 0; s < NSLOT; ++s) vcls[l][s][c32] = acc[s]; }
    else     { for (int s = 0; s < NSLOT; ++s) kcls[l][s][c32] = acc[s]; }
    __syncthreads();
  }

  float* Pbuf[2] = {p.P0, p.P1};
  int par = 0;
  float x = 0.f;   // replicated residual (identical bits in all 8 slice-blocks)

  // ================================ generation loop ================================
  for (int t = 0; t < GENLEN; ++t) {
    for (int l = 0; l < NLAYER; ++l) {
      // ------------------------------- SELF-ATTN -------------------------------
      {
        if (l == 0) {
          int tok = 0;
          if (t > 0) { consume_tri(t - 1); tok = lastAmax + 1; }
          x = p.dict_emb[tok * D + tid] + p.pe[t * D + tid];
        } else {
          x += fold(Pbuf[par]);
        }
        const float h = layernorm(x, p.ln_self_w + l * D, p.ln_self_b + l * D);
        if (l == 0) x = h;                    // SLATE quirk
        hsh[tid] = h;
        __syncthreads();

        // QKV for head sl: 192 threads, split-K x2 per column
        if (tid < 192) {
          const int mm = tid >> 6, g = tid & 63, c32 = g >> 1, half = g & 1;
          const int c = sl * DH + c32;
          const float* W = (mm == 0 ? p.Wq_s : (mm == 1 ? p.Wk_s : p.Wv_s)) + l * D * D + c;
          float acc = dotCol<128>(W, hsh, half * 128, D);
          acc += __shfl_xor(acc, 1);
          if (half == 0) {
            if (mm == 0)      qsh[c32] = acc * 0.17677669529663689f;   // dh^-0.5
            else if (mm == 1) kls[l][t][c32] = acc;
            else              vls[l][t][c32] = acc;
          }
        }
        __syncthreads();

        if (tid <= t) {
          float a = 0.f;
          #pragma unroll
          for (int r = 0; r < DH; ++r) a += qsh[r] * kls[l][tid][r];
          score[tid] = a;
        }
        __syncthreads();
        if (tid == 0) {
          float mx = -1e30f;
          for (int i = 0; i <= t; ++i) mx = fmaxf(mx, score[i]);
          float s2 = 0.f;
          for (int i = 0; i <= t; ++i) { const float e = expf(score[i] - mx); score[i] = e; s2 += e; }
          const float inv = 1.f / s2;
          for (int i = 0; i <= t; ++i) score[i] *= inv;
        }
        __syncthreads();
        if (tid < DH) {
          float a = 0.f;
          for (int pp = 0; pp <= t; ++pp) a += score[pp] * vls[l][pp][tid];
          osh[tid] = a;
        }
        __syncthreads();
        {
          const float a = dotCol<DH>(p.Wo_s + l * D * D + sl * DH * D + tid, osh, 0, D);
          cstore(&Pbuf[par ^ 1][(bb * 8 + sl) * D + tid], a);
        }
      }
      gbar(); par ^= 1;

      // ------------------------------- CROSS-ATTN -------------------------------
      {
        x += fold(Pbuf[par]);
        hsh[tid] = layernorm(x, p.ln_cross_w + l * D, p.ln_cross_b + l * D);
        __syncthreads();

        // q for head sl: 256 threads, split-K x8 per column
        {
          const int c32 = tid >> 3, sub = tid & 7;
          const float* W = p.Wq_c + l * D * D + sl * DH + c32;
          float acc = dotCol<32>(W, hsh, sub * 32, D);
          acc += __shfl_xor(acc, 1);
          acc += __shfl_xor(acc, 2);
          acc += __shfl_xor(acc, 4);
          if (sub == 0) qsh[c32] = acc * 0.17677669529663689f;
        }
        __syncthreads();
        if (tid < NSLOT) {
          float a = 0.f;
          #pragma unroll
          for (int r = 0; r < DH; ++r) a += qsh[r] * kcls[l][tid][r];
          score[tid] = a;
        }
        __syncthreads();
        if (tid == 0) {
          float mx = -1e30f;
          for (int i = 0; i < NSLOT; ++i) mx = fmaxf(mx, score[i]);
          float s2 = 0.f;
          for (int i = 0; i < NSLOT; ++i) { const float e = expf(score[i] - mx); score[i] = e; s2 += e; }
          const float inv = 1.f / s2;
          for (int i = 0; i < NSLOT; ++i) score[i] *= inv;
        }
        __syncthreads();
        if (tid < DH) {
          float a = 0.f;
          #pragma unroll
          for (int s = 0; s < NSLOT; ++s) a += score[s] * vcls[l][s][tid];
          osh[tid] = a;
        }
        __syncthreads();
        {
          const float a = dotCol<DH>(p.Wo_c + l * D * D + sl * DH * D + tid, osh, 0, D);
          cstore(&Pbuf[par ^ 1][(bb * 8 + sl) * D + tid], a);
        }
      }
      gbar(); par ^= 1;

      // ---------------------------------- FFN ----------------------------------
      {
        x += fold(Pbuf[par]);
        hsh[tid] = layernorm(x, p.ln_ffn_w + l * D, p.ln_ffn_b + l * D);
        __syncthreads();

        // W1 slice: 128 cols, split-K x2
        {
          const int c128 = tid >> 1, half = tid & 1, c = sl * 128 + c128;
          float acc = dotCol<128>(p.W1 + l * D * FFDIM + c, hsh, half * 128, FFDIM);
          acc += __shfl_xor(acc, 1);
          if (half == 0) ash[c128] = fmaxf(acc + p.b1[l * FFDIM + c], 0.f);
        }
        __syncthreads();
        // W2 row-slice partial (b2 folded into slice 0)
        {
          float acc = dotCol<128>(p.W2 + l * FFDIM * D + sl * 128 * D + tid, ash, 0, D);
          if (sl == 0) acc += p.b2[l * D + tid];
          cstore(&Pbuf[par ^ 1][(bb * 8 + sl) * D + tid], acc);
        }
        __syncthreads();
      }
      gbar(); par ^= 1;
    }

    // --------------------------------- LOGITS ---------------------------------
    {
      x += fold(Pbuf[par]);
      hsh[tid] = layernorm(x, p.ln_f_w, p.ln_f_b);
      __syncthreads();
      heldLogit = dotCol<256>(p.W_out + sl * 256 + tid, hsh, 0, VOCAB);

      sval[tid] = heldLogit; sidx[tid] = tid;
      __syncthreads();
      for (int s = 128; s; s >>= 1) {
        if (tid < s) {
          float v2 = sval[tid + s]; int i2 = sidx[tid + s];
          if (v2 > sval[tid] || (v2 == sval[tid] && i2 < sidx[tid])) { sval[tid] = v2; sidx[tid] = i2; }
        }
        __syncthreads();
      }
      const float smax = sval[0]; const int sarg = sidx[0];
      __syncthreads();
      const float ssum = blockSum(expf(heldLogit - smax), red);
      if (tid == 0) {
        cstore(&p.tri[(bb * 8 + sl) * 8 + 0], smax);
        cstore(&p.tri[(bb * 8 + sl) * 8 + 1], ssum);
        cstore(&p.tri[(bb * 8 + sl) * 8 + 2], (float)sarg);
      }
      __syncthreads();
    }
    gbar();
  }

  // ------------------------------ final step output ------------------------------
  consume_tri(GENLEN - 1);
}

extern "C" void kernel_launch(void* const* d_in, const int* in_sizes, int n_in,
                              void* d_out, int out_size, void* d_ws, size_t ws_size,
                              hipStream_t stream)
{
  Params p;
  const float* const* in = (const float* const*)d_in;
  p.slots = in[0];  p.W_slot_proj = in[1]; p.dict_emb = in[2]; p.pe = in[3];
  p.ln_self_w = in[4];  p.ln_self_b = in[5];
  p.Wq_s = in[6];  p.Wk_s = in[7];  p.Wv_s = in[8];  p.Wo_s = in[9];
  p.ln_cross_w = in[10]; p.ln_cross_b = in[11];
  p.Wq_c = in[12]; p.Wk_c = in[13]; p.Wv_c = in[14]; p.Wo_c = in[15];
  p.ln_ffn_w = in[16]; p.ln_ffn_b = in[17];
  p.W1 = in[18]; p.b1 = in[19]; p.W2 = in[20]; p.b2 = in[21];
  p.ln_f_w = in[22]; p.ln_f_b = in[23]; p.W_out = in[24];

  p.bars = (unsigned long long*)d_ws;                  // 8 groups x 128 ull (1 KB each)
  float* ws = (float*)d_ws + BATCH * 128 * 2;
  p.enc = ws;  ws += BATCH * NSLOT * D;
  p.P0  = ws;  ws += BATCH * 8 * D;
  p.P1  = ws;  ws += BATCH * 8 * D;
  p.tri = ws;  ws += BATCH * 8 * 8;

  p.out_z  = (float*)d_out;
  p.out_lp = (float*)d_out + BATCH * VOCAB * GENLEN;

  hipMemsetAsync(d_ws, 0, BATCH * 128 * sizeof(unsigned long long), stream);
  hipMemsetAsync(d_out, 0, (size_t)out_size * sizeof(float), stream);

  mega_kernel<<<64, 256, 0, stream>>>(p);
}